// Round 3
// baseline (210.232 us; speedup 1.0000x reference)
//
#include <hip/hip_runtime.h>

// Problem constants (from reference setup_inputs)
#define LATDIM 128     // d
#define ANUM   64      // anchor sets A
#define NNODES 10000   // N
#define PERIOD 625     // period of (64*i mod 10000); gcd(64,10000)=16
#define TN     16      // n per main block (10000 = 625 * 16, no tail)
#define SBLK   625     // one block per residue s; also one out-tile each

// ---------------------------------------------------------------------------
// Verified algebra (r3/r4/r6/r8 passed, absmax 9.8e-4):
//   out[n,o] = (1/A)*sum_a dists[a,n]*P[a,o] + T2b[n%625,o]
//   P[a,o]   = sum_k E[anchor[a],k]*W[o,k]
//   T2b[s,o] = b[o] + (1/A)*sum_k S[s,k]*W[o,128+k], S[s,k]=sum_a E[(64s+a)%N,k]
//
// r10 delta: r9's cooperative launch never ran (absmax 0.439 == max|ref| of a
// zeroed output -> launch rejected under graph capture). Same fusion, but
// REGULAR launch + provably-safe arrival barrier:
//   - 625 blocks, 36.9 KB LDS -> 4 blocks/CU by LDS, min capacity 1024 >= 625
//     => all blocks co-resident => no deadlock; spin bounded anyway.
//   - counter zeroed by 4-byte hipMemsetAsync on-stream (capturable, after
//     the harness poison fill in stream order).
//   - release: __syncthreads (per-wave vmcnt drain) + tid0 __threadfence
//     (XCD-L2 writeback) + release-add; acquire: acquire-load spin + fence.
//   - phase B: dists tile staged to LDS in ONE dwordx4/thread (was 64
//     serialized scalar 64B loads).
// ---------------------------------------------------------------------------

__global__ __launch_bounds__(256) void fused_kernel(
    const float* __restrict__ embeds,   // [N, d] fp32
    const float* __restrict__ dists,    // [A, N] fp32
    const float* __restrict__ W,        // [d, 2d] fp32 row-major
    const float* __restrict__ b,        // [d] fp32
    const int*   __restrict__ anchor,   // [A] int32
    float* __restrict__ P,              // [A, d]   (ws)
    float* __restrict__ T2b,            // [625, d] (ws)
    unsigned int* __restrict__ cnt,     // [1]      (ws, memset to 0)
    float* __restrict__ out)            // [N, d] fp32
{
    __shared__ float P_s[ANUM * LATDIM];    // 32 KB; phase-A arrays alias here
    __shared__ float D_s[ANUM * TN];        // 4 KB dists tile (phase B)
    float* X_s = P_s;                       // [128]
    float* R_s = P_s + LATDIM;              // [128]
    float (*Xp)[LATDIM] = (float (*)[LATDIM])(P_s + 2 * LATDIM);  // [8][128]

    const int tid = threadIdx.x;
    const int bid = blockIdx.x;             // 0..624
    const int o   = tid & 127;              // output channel
    const int h   = tid >> 7;               // split-k half
    const float4* X_s4 = (const float4*)X_s;

    // ======================= Phase A: T2b[s=bid] =======================
    {
        const int row0 = (64 * bid) % NNODES;   // contiguous span start
        const int c4 = tid & 31;                // float4 column 0..31
        const int hg = tid >> 5;                // row group 0..7
        float4 sum = {0.f, 0.f, 0.f, 0.f};
        #pragma unroll
        for (int i = 0; i < 8; ++i) {
            int row = row0 + 8 * i + hg;
            if (row >= NNODES) row -= NNODES;   // single wrap suffices
            float4 v = *((const float4*)(embeds + (size_t)row * LATDIM) + c4);
            sum.x += v.x; sum.y += v.y; sum.z += v.z; sum.w += v.w;
        }
        ((float4*)&Xp[hg][0])[c4] = sum;
        __syncthreads();
        if (tid < LATDIM) {                     // conflict-free combine
            float t = Xp[0][tid];
            #pragma unroll
            for (int g = 1; g < 8; ++g) t += Xp[g][tid];
            X_s[tid] = t;
        }
        __syncthreads();

        const float4* Wr =
            (const float4*)(W + (size_t)o * (2 * LATDIM) + LATDIM + h * 64);
        float acc = 0.f;
        #pragma unroll
        for (int k4 = 0; k4 < 16; ++k4) {
            float4 w4 = Wr[k4];
            float4 x4 = X_s4[h * 16 + k4];      // LDS broadcast
            acc += w4.x * x4.x + w4.y * x4.y + w4.z * x4.z + w4.w * x4.w;
        }
        if (h == 1) R_s[o] = acc;
        __syncthreads();
        if (h == 0)
            T2b[(size_t)bid * LATDIM + o] =
                b[o] + (acc + R_s[o]) * (1.0f / ANUM);
    }

    // ============ Phase A': P[a=bid] for the first 64 blocks ============
    if (bid < ANUM) {
        __syncthreads();                        // phase-A R_s readers done
        if (tid < 32) {
            ((float4*)X_s)[tid] =
                *((const float4*)(embeds + (size_t)anchor[bid] * LATDIM) + tid);
        }
        __syncthreads();
        const float4* Wr = (const float4*)(W + (size_t)o * (2 * LATDIM) + h * 64);
        float acc = 0.f;
        #pragma unroll
        for (int k4 = 0; k4 < 16; ++k4) {
            float4 w4 = Wr[k4];
            float4 x4 = X_s4[h * 16 + k4];      // LDS broadcast
            acc += w4.x * x4.x + w4.y * x4.y + w4.z * x4.z + w4.w * x4.w;
        }
        if (h == 1) R_s[o] = acc;
        __syncthreads();
        if (h == 0) P[(size_t)bid * LATDIM + o] = acc + R_s[o];
    }

    // ============== arrival barrier (all 625 blocks resident) ==========
    __syncthreads();            // drains each wave's outstanding stores
    if (tid == 0) {
        __threadfence();        // release: XCD-L2 writeback of T2b/P
        __hip_atomic_fetch_add(cnt, 1u, __ATOMIC_ACQ_REL,
                               __HIP_MEMORY_SCOPE_AGENT);
        int guard = 0;
        while (__hip_atomic_load(cnt, __ATOMIC_ACQUIRE,
                                 __HIP_MEMORY_SCOPE_AGENT) < (unsigned)SBLK &&
               guard < (1 << 24)) {
            __builtin_amdgcn_s_sleep(4);
            ++guard;
        }
    }
    __syncthreads();
    __threadfence();            // acquire side for all waves

    // ================ Phase B: out tile [bid*16, bid*16+16) ============
    {   // stage P (32 KB) coalesced float4 + dists tile in ONE dwordx4/thread
        float4* P_s4 = (float4*)P_s;
        const float4* Pg = (const float4*)P;
        #pragma unroll
        for (int it = 0; it < (ANUM * LATDIM / 4) / 256; ++it)
            P_s4[it * 256 + tid] = Pg[it * 256 + tid];
        // thread t -> a = t>>2, n4 = t&3 : D_s[a][4*n4..4*n4+3]
        ((float4*)D_s)[tid] = *(const float4*)(
            dists + (size_t)(tid >> 2) * NNODES + bid * TN + 4 * (tid & 3));
    }
    __syncthreads();

    const int lane = tid & 63;
    const int w    = __builtin_amdgcn_readfirstlane(tid >> 6);  // uniform 0..3
    const int oo   = (w & 1) * 64 + lane;       // output channel
    const int nc   = w >> 1;                    // n-chunk within block
    const int nb   = bid * TN + nc * 8;         // uniform; always in-range

    float acc[8] = {};
    #pragma unroll
    for (int a = 0; a < ANUM; ++a) {
        const float p = P_s[a * LATDIM + oo];   // per-lane, conflict-free
        const float4 d0 = ((const float4*)(D_s + a * TN + nc * 8))[0];  // bcast
        const float4 d1 = ((const float4*)(D_s + a * TN + nc * 8))[1];  // bcast
        acc[0] += d0.x * p; acc[1] += d0.y * p;
        acc[2] += d0.z * p; acc[3] += d0.w * p;
        acc[4] += d1.x * p; acc[5] += d1.y * p;
        acc[6] += d1.z * p; acc[7] += d1.w * p;
    }

    #pragma unroll
    for (int j = 0; j < 8; ++j) {
        const int n = nb + j;
        const int s = n % PERIOD;
        out[(size_t)n * LATDIM + oo] =
            acc[j] * (1.0f / ANUM) + T2b[(size_t)s * LATDIM + oo];
    }
}

extern "C" void kernel_launch(void* const* d_in, const int* in_sizes, int n_in,
                              void* d_out, int out_size, void* d_ws, size_t ws_size,
                              hipStream_t stream) {
    const float* embeds = (const float*)d_in[0];   // [10000,128] fp32
    const float* dists  = (const float*)d_in[1];   // [64,10000]  fp32
    const float* W      = (const float*)d_in[2];   // [128,256]   fp32
    const float* b      = (const float*)d_in[3];   // [128]       fp32
    const int*   anchor = (const int*)d_in[4];     // [64]        int32
    float* out = (float*)d_out;                    // [10000,128] fp32

    float* P   = (float*)d_ws;            // 64*128 floats   = 32 KB
    float* T2b = P + ANUM * LATDIM;       // 625*128 floats  = 320 KB
    unsigned int* cnt = (unsigned int*)(T2b + PERIOD * LATDIM);  // 4 B

    hipMemsetAsync(cnt, 0, sizeof(unsigned int), stream);  // capturable
    fused_kernel<<<SBLK, 256, 0, stream>>>(embeds, dists, W, b, anchor,
                                           P, T2b, cnt, out);
}

// Round 4
// 88.134 us; speedup vs baseline: 2.3854x; 2.3854x over previous
//
#include <hip/hip_runtime.h>

// Problem constants (from reference setup_inputs)
#define LATDIM 128     // d
#define ANUM   64      // anchor sets A
#define NNODES 10000   // N
#define PERIOD 625     // period of (64*i mod 10000); gcd(64,10000)=16
#define NJ     16      // outputs per block: n = s + 625*j, j in [0,16)

// ---------------------------------------------------------------------------
// Verified algebra (r3..r8 passed, absmax 9.8e-4):
//   out[n,o] = b[o] + (1/A)*( sum_k G[n,k]*W[o,k] + sum_k S[s,k]*W[o,128+k] )
//     where s = n mod 625,
//           G[n,k] = sum_a dists[a,n]*E[anchor[a],k]      (exact reordering
//              of the old P-route: swaps the a-sum and k-sum — linear, fp32
//              rounding within the 8.8e-3 threshold)
//           S[s,k] = sum_{r in [64s,64s+64) mod N} E[r,k]
//
// r11 delta: ZERO-DEPENDENCY single launch. r10 proved grid barriers cost
// ~140us (spin contention); r5 agreed. Remap block := residue s owning
// n in {s+625j}: T2b[s] is produced+consumed locally, P is never formed
// (G-route, 0.42M MAC/block vs 1.16M redundant-P). No workspace, no
// barrier, no memset — one plain launch.
//   - 625 blocks x 256 thr, LDS 44.75KB -> 3 blocks/CU, all co-resident.
//   - bijective XCD swizzle (625=8*78+1): consecutive s per XCD -> dists
//     lines (shared by 16 consecutive s) and embed windows stay L2-local.
//   - all matmul inner loops use wave-uniform LDS BROADCAST operands
//     (D in G-phase, G/S in final phase) — broadcast is conflict-free.
//   - dists: 1024-elem gather/block, disjoint across blocks (2.5MB unique).
//   - W streamed from L2 (128KB/block = W exactly once; L2-resident/XCD).
// ---------------------------------------------------------------------------

__global__ __launch_bounds__(256) void fused_kernel(
    const float* __restrict__ embeds,   // [N, d] fp32
    const float* __restrict__ dists,    // [A, N] fp32
    const float* __restrict__ W,        // [d, 2d] fp32 row-major
    const float* __restrict__ b,        // [d] fp32
    const int*   __restrict__ anchor,   // [A] int32
    float* __restrict__ out)            // [N, d] fp32
{
    __shared__ float EA[ANUM * LATDIM];   // 32 KB; first 8 KB reused as R late
    __shared__ float G_s[NJ * LATDIM];    // 8 KB; first 4 KB = Xp early
    __shared__ float D_s[ANUM * NJ];      // 4 KB
    __shared__ float S_s[LATDIM];         // 512 B
    __shared__ int   An[ANUM];            // 256 B   (total 44.75 KB)

    const int tid = threadIdx.x;
    // bijective XCD swizzle (m204 form, q=78, r=1): consecutive s on one XCD
    const int orig = blockIdx.x;
    const int xcd = orig & 7, ii = orig >> 3;
    const int s = (xcd == 0) ? ii : (79 + (xcd - 1) * 78 + ii);

    // ---- stage: anchor ids, dists gather, S row-group partials ----
    if (tid < ANUM) An[tid] = anchor[tid];
    #pragma unroll
    for (int it = 0; it < 4; ++it) {
        int idx = it * 256 + tid;           // 0..1023
        int a = idx >> 4, j = idx & 15;     // n_j = s + 625*j <= 9999
        D_s[a * NJ + j] = dists[(size_t)a * NNODES + (s + PERIOD * j)];
    }
    float (*Xp)[LATDIM] = (float (*)[LATDIM])G_s;   // 4 KB scratch in G_s
    {
        const int row0 = (64 * s) % NNODES;         // span [row0, row0+64)
        const int c4 = tid & 31, hg = tid >> 5;
        float4 sum = {0.f, 0.f, 0.f, 0.f};
        #pragma unroll
        for (int i = 0; i < 8; ++i) {
            int row = row0 + 8 * i + hg;
            if (row >= NNODES) row -= NNODES;       // single wrap suffices
            float4 v = *((const float4*)(embeds + (size_t)row * LATDIM) + c4);
            sum.x += v.x; sum.y += v.y; sum.z += v.z; sum.w += v.w;
        }
        ((float4*)&Xp[hg][0])[c4] = sum;
    }
    __syncthreads();        // An, D_s, Xp ready

    // ---- combine S (tid<128) + stage EA (all threads) ----
    if (tid < LATDIM) {
        float t = Xp[0][tid];
        #pragma unroll
        for (int g = 1; g < 8; ++g) t += Xp[g][tid];
        S_s[tid] = t;
    }
    #pragma unroll
    for (int it = 0; it < 8; ++it) {
        int idx = it * 256 + tid;           // 0..2047
        int a = idx >> 5, c4 = idx & 31;
        ((float4*)EA)[a * 32 + c4] =
            *((const float4*)(embeds + (size_t)An[a] * LATDIM) + c4);
    }
    __syncthreads();        // S_s, EA ready; Xp dead -> G_s writable

    // ---- G[j,k] = sum_a D[a,j] * EA[a,k] ----
    {
        const int k  = tid & 127;           // lanes -> consecutive k (2/bank)
        const int jh = tid >> 7;            // wave-uniform j-octet
        float g[8] = {};
        #pragma unroll
        for (int a = 0; a < ANUM; ++a) {
            const float  ea = EA[a * LATDIM + k];
            const float4 d0 = ((const float4*)(D_s + a * NJ + jh * 8))[0]; // bcast
            const float4 d1 = ((const float4*)(D_s + a * NJ + jh * 8))[1]; // bcast
            g[0] += d0.x * ea; g[1] += d0.y * ea;
            g[2] += d0.z * ea; g[3] += d0.w * ea;
            g[4] += d1.x * ea; g[5] += d1.y * ea;
            g[6] += d1.z * ea; g[7] += d1.w * ea;
        }
        #pragma unroll
        for (int jj = 0; jj < 8; ++jj)
            G_s[(jh * 8 + jj) * LATDIM + k] = g[jj];    // consecutive k: ok
    }
    __syncthreads();        // G ready; EA dead

    // ---- final: out[s+625j, o] = b[o] + (G[j]·W1(o) + S·W2(o))/A ----
    {
        const int o = tid & 127;            // output channel
        const int h = tid >> 7;             // split-k half, wave-uniform
        const float4* Wr1 = (const float4*)(W + (size_t)o * (2 * LATDIM) + h * 64);
        const float4* Wr2 = (const float4*)(W + (size_t)o * (2 * LATDIM) + LATDIM + h * 64);
        const float4* S4  = (const float4*)S_s;
        const float4* G4  = (const float4*)G_s;
        float acc[NJ] = {};
        float sacc = 0.f;
        #pragma unroll
        for (int q = 0; q < 16; ++q) {
            const float4 w1 = Wr1[q];               // L2 stream, this o-row
            const float4 w2 = Wr2[q];
            const float4 sv = S4[h * 16 + q];       // LDS broadcast
            sacc += sv.x*w2.x + sv.y*w2.y + sv.z*w2.z + sv.w*w2.w;
            #pragma unroll
            for (int j = 0; j < NJ; ++j) {
                const float4 gv = G4[j * 32 + h * 16 + q];  // LDS broadcast
                acc[j] += gv.x*w1.x + gv.y*w1.y + gv.z*w1.z + gv.w*w1.w;
            }
        }
        float* R = EA;                      // 8 KB alias; EA dead since sync
        if (h == 1) {
            #pragma unroll
            for (int j = 0; j < NJ; ++j)
                R[j * LATDIM + o] = acc[j] + sacc;
        }
        __syncthreads();
        if (h == 0) {
            const float bias = b[o];
            #pragma unroll
            for (int j = 0; j < NJ; ++j) {
                const int n = s + PERIOD * j;
                out[(size_t)n * LATDIM + o] =
                    bias + (acc[j] + sacc + R[j * LATDIM + o]) * (1.0f / ANUM);
            }
        }
    }
}

extern "C" void kernel_launch(void* const* d_in, const int* in_sizes, int n_in,
                              void* d_out, int out_size, void* d_ws, size_t ws_size,
                              hipStream_t stream) {
    const float* embeds = (const float*)d_in[0];   // [10000,128] fp32
    const float* dists  = (const float*)d_in[1];   // [64,10000]  fp32
    const float* W      = (const float*)d_in[2];   // [128,256]   fp32
    const float* b      = (const float*)d_in[3];   // [128]       fp32
    const int*   anchor = (const int*)d_in[4];     // [64]        int32
    float* out = (float*)d_out;                    // [10000,128] fp32

    (void)d_ws; (void)ws_size;   // no workspace, no barrier, no memset
    fused_kernel<<<PERIOD, 256, 0, stream>>>(embeds, dists, W, b, anchor, out);
}